// Round 5
// baseline (357.565 us; speedup 1.0000x reference)
//
#include <hip/hip_runtime.h>

// SelfAttention (SAGAN-style) on MI355X.
// B=2, C=64, C8=8, H=W=96, N=9216.  out = gamma * Attn(g,f,h) + x
//   K = f = (Wq/sq) x + bq   (pre-scaled by log2e; softmax in exp2 domain)
//   Q = g = (Wk/sk) x + bk
//   V = h = (Wv/sv) x + bv
// softmax over keys i; head_dim 8 (zero-padded to MFMA K=32), dv=64.
//
// R5: R4 + exp2-window shift. R4 pathology: bound-max M = |Q|*max|K'| put the
// softmax bulk at p ~ 2^-17 for large-|Q| queries -> f16 subnormal; MFMA
// flushes subnormal inputs -> numerator lost mass the denominator kept ->
// absmax 0.276. Fix: p = exp2(S - M + 12). S<=M so p<=4096 (no f16 overflow);
// underflow pushed to S < M-26 (negligible mass). Single pass + explicit K/V
// double buffers + __launch_bounds__(256,4) retained from R4.

#define N_PIX 9216
#define N_B   2
#define N_C   64

typedef _Float16 half8  __attribute__((ext_vector_type(8)));
typedef _Float16 half4v __attribute__((ext_vector_type(4)));
typedef float    float4v __attribute__((ext_vector_type(4)));

#define LOG2E 1.44269504088896340736f
#define EXP_SHIFT 12.0f

// ---------------------------------------------------------------- k_sigma
__global__ __launch_bounds__(64) void k_sigma(const float* __restrict__ Wq,
                                              const float* __restrict__ Wk,
                                              const float* __restrict__ Wv,
                                              float* __restrict__ sig) {
  __shared__ float G8[8][8];
  __shared__ float Wl[64 * 64];
  __shared__ _Float16 Wh[64 * 80];
  __shared__ _Float16 Gh[64 * 80];
  const int t = threadIdx.x;
  const int mat = blockIdx.x;
  if (mat < 2) {
    const float* W = (mat == 0) ? Wq : Wk;
    const int i = t >> 3, j = t & 7;
    float g = 0.f;
    for (int c = 0; c < 64; ++c) g += W[i * 64 + c] * W[j * 64 + c];
    G8[i][j] = g;
    __syncthreads();
    const int L = t & 7;
    float G0[8], Gr[8];
    for (int k = 0; k < 8; ++k) { G0[k] = G8[L][k]; Gr[k] = G0[k]; }
    for (int it = 0; it < 8; ++it) {
      float g2[8] = {0, 0, 0, 0, 0, 0, 0, 0};
      for (int k = 0; k < 8; ++k) {
        float gik = Gr[k];
        for (int jj = 0; jj < 8; ++jj) g2[jj] += gik * __shfl(Gr[jj], k, 64);
      }
      float mx = 0.f;
      for (int jj = 0; jj < 8; ++jj) mx = fmaxf(mx, fabsf(g2[jj]));
      for (int d = 1; d < 8; d <<= 1) mx = fmaxf(mx, __shfl_xor(mx, d, 64));
      float r = 1.f / mx;
      for (int jj = 0; jj < 8; ++jj) Gr[jj] = g2[jj] * r;
    }
    float u = 0.f;
    for (int jj = 0; jj < 8; ++jj) u += Gr[jj];
    float y = 0.f;
    for (int k = 0; k < 8; ++k) y += G0[k] * __shfl(u, k, 64);
    float nu = u * y, de = u * u;
    for (int d = 1; d < 8; d <<= 1) { nu += __shfl_xor(nu, d, 64); de += __shfl_xor(de, d, 64); }
    if (t == 0) sig[mat] = sqrtf(nu / de);
  } else {
    for (int idx = t; idx < 4096; idx += 64) Wl[idx] = Wv[idx];
    __syncthreads();
    for (int idx = t; idx < 4096; idx += 64) Wh[(idx >> 6) * 80 + (idx & 63)] = (_Float16)Wl[idx];
    __syncthreads();
    const int lane15 = t & 15, quad = t >> 4;
    half8 fr[4][2];
    for (int rb = 0; rb < 4; ++rb)
      for (int kc = 0; kc < 2; ++kc)
        fr[rb][kc] = *(const half8*)&Wh[(lane15 + 16 * rb) * 80 + 32 * kc + 8 * quad];
    float4v D[4][4];
    for (int mb = 0; mb < 4; ++mb) for (int nb = 0; nb < 4; ++nb) D[mb][nb] = (float4v){0.f, 0.f, 0.f, 0.f};
    for (int kc = 0; kc < 2; ++kc)
      for (int mb = 0; mb < 4; ++mb)
        for (int nb = 0; nb < 4; ++nb)
          D[mb][nb] = __builtin_amdgcn_mfma_f32_16x16x32_f16(fr[mb][kc], fr[nb][kc], D[mb][nb], 0, 0, 0);
    for (int it = 0; it < 8; ++it) {
      float mx = 0.f;
      for (int mb = 0; mb < 4; ++mb) for (int nb = 0; nb < 4; ++nb) for (int r = 0; r < 4; ++r)
        mx = fmaxf(mx, fabsf(D[mb][nb][r]));
      for (int d = 1; d < 64; d <<= 1) mx = fmaxf(mx, __shfl_xor(mx, d, 64));
      float rs = 1.f / mx;
      for (int mb = 0; mb < 4; ++mb) for (int nb = 0; nb < 4; ++nb) for (int r = 0; r < 4; ++r)
        Gh[(4 * quad + r + 16 * mb) * 80 + lane15 + 16 * nb] = (_Float16)(D[mb][nb][r] * rs);
      __syncthreads();
      if (it == 7) break;
      for (int rb = 0; rb < 4; ++rb)
        for (int kc = 0; kc < 2; ++kc)
          fr[rb][kc] = *(const half8*)&Gh[(lane15 + 16 * rb) * 80 + 32 * kc + 8 * quad];
      for (int mb = 0; mb < 4; ++mb) for (int nb = 0; nb < 4; ++nb) D[mb][nb] = (float4v){0.f, 0.f, 0.f, 0.f};
      for (int kc = 0; kc < 2; ++kc)
        for (int mb = 0; mb < 4; ++mb)
          for (int nb = 0; nb < 4; ++nb)
            D[mb][nb] = __builtin_amdgcn_mfma_f32_16x16x32_f16(fr[mb][kc], fr[nb][kc], D[mb][nb], 0, 0, 0);
      __syncthreads();
    }
    float u = 0.f;
    for (int c = 0; c < 64; ++c) u += (float)Gh[t * 80 + c];
    float z = 0.f;
    for (int i2 = 0; i2 < 64; ++i2) z += Wl[i2 * 64 + t] * __shfl(u, i2, 64);
    float nu = z * z, de = u * u;
    for (int d = 1; d < 64; d <<= 1) { nu += __shfl_xor(nu, d, 64); de += __shfl_xor(de, d, 64); }
    if (t == 0) sig[2] = sqrtf(nu / de);
  }
}

// ---------------------------------------------------------------- k_wconv
// Also zero-inits maxKu[2] (workspace is poisoned before every launch).
__global__ __launch_bounds__(128) void k_wconv(const float* __restrict__ Wq, const float* __restrict__ bq,
                                               const float* __restrict__ Wk, const float* __restrict__ bk,
                                               const float* __restrict__ Wv, const float* __restrict__ bv,
                                               const float* __restrict__ sig,
                                               _Float16* __restrict__ W16, float* __restrict__ b80,
                                               unsigned* __restrict__ maxKu) {
  const float iq = LOG2E / sig[0], ik = 1.0f / sig[1], iv = 1.0f / sig[2];
  const int t = threadIdx.x;
  for (int idx = t; idx < 80 * 64; idx += 128) {
    const int m = idx >> 6, c = idx & 63;
    float v;
    if (m < 8)       v = Wq[m * 64 + c] * iq;
    else if (m < 16) v = Wk[(m - 8) * 64 + c] * ik;
    else             v = Wv[(m - 16) * 64 + c] * iv;
    W16[idx] = (_Float16)v;
  }
  if (t < 80) {
    float v;
    if (t < 8)       v = bq[t] * LOG2E;
    else if (t < 16) v = bk[t - 8];
    else             v = bv[t - 16];
    b80[t] = v;
  }
  if (t < 2) maxKu[t] = 0u;
}

// ---------------------------------------------------------------- k_fgh
// Also computes max_i |K'_i|^2 per batch via wave butterfly max + atomicMax
// on float bits (nonnegative -> uint order == float order).
__global__ __launch_bounds__(256) void k_fgh(const float* __restrict__ x,
                                             const _Float16* __restrict__ W16,
                                             const float* __restrict__ b80,
                                             _Float16* __restrict__ K16,
                                             _Float16* __restrict__ Q16,
                                             _Float16* __restrict__ VT16,
                                             unsigned* __restrict__ maxKu) {
  const int wave = threadIdx.x >> 6;
  const int lane = threadIdx.x & 63;
  const int lane15 = lane & 15, quad = lane >> 4;
  const int tile = blockIdx.x * 4 + wave;
  const int b = tile / 576;
  const int n = (tile % 576) * 16 + lane15;
  half8 wf[5][2];
  for (int mb = 0; mb < 5; ++mb)
    for (int kc = 0; kc < 2; ++kc)
      wf[mb][kc] = *(const half8*)&W16[(lane15 + 16 * mb) * 64 + 32 * kc + 8 * quad];
  float4v acc[5];
  for (int mb = 0; mb < 5; ++mb) acc[mb] = *(const float4v*)&b80[16 * mb + 4 * quad];
  const float* xb = x + (size_t)b * N_C * N_PIX;
  for (int kc = 0; kc < 2; ++kc) {
    half8 bf;
    for (int j = 0; j < 8; ++j)
      bf[j] = (_Float16)xb[(size_t)(32 * kc + 8 * quad + j) * N_PIX + n];
    for (int mb = 0; mb < 5; ++mb)
      acc[mb] = __builtin_amdgcn_mfma_f32_16x16x32_f16(wf[mb][kc], bf, acc[mb], 0, 0, 0);
  }
  {
    _Float16* dstK = K16 + ((size_t)b * N_PIX + n) * 8;
    _Float16* dstQ = Q16 + ((size_t)b * N_PIX + n) * 8;
    for (int r = 0; r < 4; ++r) {
      const int m = 4 * quad + r;
      const _Float16 v = (_Float16)acc[0][r];
      if (m < 8) dstK[m] = v; else dstQ[m - 8] = v;
    }
  }
  for (int mb = 1; mb < 5; ++mb)
    for (int r = 0; r < 4; ++r) {
      const int c = 4 * quad + r + 16 * (mb - 1);
      VT16[((size_t)b * N_C + c) * N_PIX + n] = (_Float16)acc[mb][r];
    }
  // max |K'|^2: rows m=4*quad+r of acc[0] are K' rows for quad<2, col = pixel
  float sq = 0.f;
  if (quad < 2)
    for (int r = 0; r < 4; ++r) sq += acc[0][r] * acc[0][r];
  sq += __shfl_xor(sq, 16, 64);  // quads (0,1) now hold full per-pixel norm^2
  for (int d = 1; d < 64; d <<= 1) sq = fmaxf(sq, __shfl_xor(sq, d, 64));
  if (lane == 0) atomicMax(&maxKu[b], __float_as_uint(sq));
}

// ---------------------------------------------------------------- k_attn
// Block = 4 waves, one 16-query tile; wave w covers keys [w*2304,(w+1)*2304).
// Single pass: p = exp2(S - M + 12), M = |Q|*max|K'| (Cauchy-Schwarz bound).
// 64-key rounds; explicit K+V double-buffers; __launch_bounds__(256,4).

#define KEYS_PER_WAVE (N_PIX / 4)           // 2304
#define ROUNDS        (KEYS_PER_WAVE / 64)  // 36

__device__ __forceinline__ void loadK4(half8 (&kf)[4], const _Float16* Kb,
                                       int i0, int lane15, int quad) {
  // quad0 lanes carry real K data (k=0..7); quads 1-3 keep their zero init
  // (qf is zero there, so A-operand content is irrelevant but must not be NaN).
#pragma unroll
  for (int t = 0; t < 4; ++t)
    if (quad == 0)
      kf[t] = *(const half8*)(Kb + (size_t)(i0 + 16 * t + lane15) * 8);
}

__device__ __forceinline__ void loadV8(half8 (&vf)[8], const _Float16* Vb,
                                       int i0, int lane15, int quad) {
#pragma unroll
  for (int cb = 0; cb < 4; ++cb)
#pragma unroll
    for (int t2 = 0; t2 < 2; ++t2)
      vf[2 * cb + t2] = *(const half8*)(Vb + (size_t)(lane15 + 16 * cb) * N_PIX + i0 + 32 * t2 + 8 * quad);
}

__device__ __forceinline__ void sp_round(const half8 (&kf)[4], const half8 (&vf)[8],
                                         half8 (&kn)[4], half8 (&vn)[8],
                                         bool pref, int i1,
                                         const half8 qf, float4v (&acc)[4],
                                         float& lsum, const float M,
                                         const _Float16* Kb, const _Float16* Vb,
                                         _Float16* Pl, int lane15, int quad) {
  const float4v f4z = {0.f, 0.f, 0.f, 0.f};
  // prefetch next round first: max lead time for the VMEM queue
  if (pref) { loadK4(kn, Kb, i1, lane15, quad); loadV8(vn, Vb, i1, lane15, quad); }
  float4v s0 = __builtin_amdgcn_mfma_f32_16x16x32_f16(kf[0], qf, f4z, 0, 0, 0);
  float4v s1 = __builtin_amdgcn_mfma_f32_16x16x32_f16(kf[1], qf, f4z, 0, 0, 0);
  float4v s2 = __builtin_amdgcn_mfma_f32_16x16x32_f16(kf[2], qf, f4z, 0, 0, 0);
  float4v s3 = __builtin_amdgcn_mfma_f32_16x16x32_f16(kf[3], qf, f4z, 0, 0, 0);
  float4v sv[4] = {s0, s1, s2, s3};
  // p = exp2(S - M + 12) in (0, 4096]: keeps the softmax bulk in f16 normal
  // range despite the bound-max overshoot. lsum accumulates the f16-ROUNDED p
  // (matches the PV numerator exactly).
#pragma unroll
  for (int t = 0; t < 4; ++t) {
    half4v h;
#pragma unroll
    for (int r = 0; r < 4; ++r) {
      const float p = __builtin_amdgcn_exp2f(sv[t][r] - M);
      h[r] = (_Float16)p;
      lsum += (float)h[r];
    }
    *(half4v*)&Pl[lane15 * 72 + 16 * t + 4 * quad] = h;
  }
  const half8 p0 = *(const half8*)&Pl[lane15 * 72 + 8 * quad];
  const half8 p1 = *(const half8*)&Pl[lane15 * 72 + 32 + 8 * quad];
#pragma unroll
  for (int cb = 0; cb < 4; ++cb) {
    acc[cb] = __builtin_amdgcn_mfma_f32_16x16x32_f16(p0, vf[2 * cb], acc[cb], 0, 0, 0);
    acc[cb] = __builtin_amdgcn_mfma_f32_16x16x32_f16(p1, vf[2 * cb + 1], acc[cb], 0, 0, 0);
  }
}

__global__ __launch_bounds__(256, 4) void k_attn(const _Float16* __restrict__ K16,
                                                 const _Float16* __restrict__ Q16,
                                                 const _Float16* __restrict__ VT16,
                                                 const unsigned* __restrict__ maxKu,
                                                 const float* __restrict__ x,
                                                 const float* __restrict__ gamma,
                                                 float* __restrict__ out) {
  __shared__ _Float16 P_lds[4][16 * 72];
  __shared__ float Lsh[4][16];
  __shared__ float Osh[4][64][17];
  const int wave = threadIdx.x >> 6;
  const int lane = threadIdx.x & 63;
  const int lane15 = lane & 15, quad = lane >> 4;
  const int tile = blockIdx.x;            // 0..1151
  const int b = tile / 576;
  const int j0 = (tile % 576) * 16;
  const float gm = gamma[0];
  const _Float16* Kb = K16 + (size_t)b * N_PIX * 8;
  const _Float16* Vb = VT16 + (size_t)b * N_C * N_PIX;
  _Float16* Pl = P_lds[wave];
  const int kbeg = wave * KEYS_PER_WAVE;
  // Q frag (B-operand): quad0 lanes hold Q[j0+lane15][k=0..7]; rest zero.
  half8 qf = {};
  if (quad == 0) qf = *(const half8*)(Q16 + ((size_t)b * N_PIX + j0 + lane15) * 8);
  // M_j = |Q_j| * max|K'| - EXP_SHIFT  (>= true row max - 12; see header)
  const float maxK = sqrtf(__uint_as_float(maxKu[b]));
  float nq2 = 0.f;
  if (quad == 0)
#pragma unroll
    for (int j = 0; j < 8; ++j) { const float qv = (float)qf[j]; nq2 += qv * qv; }
  nq2 = __shfl(nq2, lane15, 64);          // broadcast query lane15's norm to all quads
  const float M = sqrtf(nq2) * maxK - EXP_SHIFT;

  float4v acc[4];
  for (int cb = 0; cb < 4; ++cb) acc[cb] = (float4v){0.f, 0.f, 0.f, 0.f};
  float lsum = 0.f;
  half8 kA[4] = {}, kB[4] = {};           // zero once; quads 1-3 stay zero forever
  half8 vA[8], vB[8];
  loadK4(kA, Kb, kbeg, lane15, quad);
  loadV8(vA, Vb, kbeg, lane15, quad);
#pragma unroll 1
  for (int r2 = 0; r2 < ROUNDS / 2; ++r2) {
    const int i0 = kbeg + r2 * 128;
    sp_round(kA, vA, kB, vB, true, i0 + 64, qf, acc, lsum, M, Kb, Vb, Pl, lane15, quad);
    sp_round(kB, vB, kA, vA, r2 < ROUNDS / 2 - 1, i0 + 128, qf, acc, lsum, M, Kb, Vb, Pl, lane15, quad);
  }
  lsum += __shfl_xor(lsum, 16, 64);
  lsum += __shfl_xor(lsum, 32, 64);
  if (quad == 0) Lsh[wave][lane15] = lsum;
#pragma unroll
  for (int cb = 0; cb < 4; ++cb)
#pragma unroll
    for (int r = 0; r < 4; ++r) Osh[wave][lane][4 * cb + r] = acc[cb][r];
  __syncthreads();

  // merge (no exp: all waves share the same M per query)
  const int c = lane15 + 16 * wave;
  const float* xb = x + (size_t)b * N_C * N_PIX;
  float* ob = out + (size_t)b * N_C * N_PIX;
  const int jq0 = 4 * quad;
  const float lst0 = Lsh[0][jq0] + Lsh[1][jq0] + Lsh[2][jq0] + Lsh[3][jq0];
  const float lst1 = Lsh[0][jq0 + 1] + Lsh[1][jq0 + 1] + Lsh[2][jq0 + 1] + Lsh[3][jq0 + 1];
  const float lst2 = Lsh[0][jq0 + 2] + Lsh[1][jq0 + 2] + Lsh[2][jq0 + 2] + Lsh[3][jq0 + 2];
  const float lst3 = Lsh[0][jq0 + 3] + Lsh[1][jq0 + 3] + Lsh[2][jq0 + 3] + Lsh[3][jq0 + 3];
  float4v osum = {0.f, 0.f, 0.f, 0.f};
#pragma unroll
  for (int w = 0; w < 4; ++w)
#pragma unroll
    for (int r = 0; r < 4; ++r) osum[r] += Osh[w][lane][4 * wave + r];
  const size_t idx = (size_t)c * N_PIX + j0 + jq0;
  const float4v xr = *(const float4v*)(xb + idx);
  float4v o;
  o[0] = gm * osum[0] / lst0 + xr[0];
  o[1] = gm * osum[1] / lst1 + xr[1];
  o[2] = gm * osum[2] / lst2 + xr[2];
  o[3] = gm * osum[3] / lst3 + xr[3];
  *(float4v*)(ob + idx) = o;
}

// ---------------------------------------------------------------- launch
extern "C" void kernel_launch(void* const* d_in, const int* in_sizes, int n_in,
                              void* d_out, int out_size, void* d_ws, size_t ws_size,
                              hipStream_t stream) {
  const float* x     = (const float*)d_in[0];
  const float* Wq    = (const float*)d_in[1];
  const float* bq    = (const float*)d_in[2];
  const float* Wk    = (const float*)d_in[3];
  const float* bk    = (const float*)d_in[4];
  const float* Wv    = (const float*)d_in[5];
  const float* bv    = (const float*)d_in[6];
  const float* gamma = (const float*)d_in[7];
  float* out = (float*)d_out;

  char* ws = (char*)d_ws;
  float*    sig   = (float*)ws;                       // 4 floats
  unsigned* maxKu = (unsigned*)(ws + 16);             // 2 uints (float bits, >=0)
  float*    b80   = (float*)(ws + 32);                // 80 floats
  _Float16* W16   = (_Float16*)(ws + 512);            // 80*64 halves
  _Float16* K16   = (_Float16*)(ws + 10752);          // 2*9216*8
  _Float16* Q16   = (_Float16*)(ws + 10752 + 294912); // 2*9216*8
  _Float16* VT16  = (_Float16*)(ws + 10752 + 2 * 294912); // 2*64*9216

  hipLaunchKernelGGL(k_sigma, dim3(3), dim3(64), 0, stream, Wq, Wk, Wv, sig);
  hipLaunchKernelGGL(k_wconv, dim3(1), dim3(128), 0, stream, Wq, bq, Wk, bk, Wv, bv, sig, W16, b80, maxKu);
  hipLaunchKernelGGL(k_fgh, dim3(288), dim3(256), 0, stream, x, W16, b80, K16, Q16, VT16, maxKu);
  hipLaunchKernelGGL(k_attn, dim3(1152), dim3(256), 0, stream, K16, Q16, VT16, maxKu, x, gamma, out);
}

// Round 6
// 200.844 us; speedup vs baseline: 1.7803x; 1.7803x over previous
//
#include <hip/hip_runtime.h>

// SelfAttention (SAGAN-style) on MI355X.
// B=2, C=64, C8=8, H=W=96, N=9216.  out = gamma * Attn(g,f,h) + x
//   K = f = (Wq/sq) x + bq   (pre-scaled by log2e; softmax in exp2 domain)
//   Q = g = (Wk/sk) x + bk
//   V = h = (Wv/sv) x + bv
// softmax over keys i; head_dim 8 (zero-padded to MFMA K=32), dv=64.
//
// R6: cooperative block-flash k_attn. R5 pathology: explicit K/V register
// double-buffers (~140 VGPRs) lost the allocator fight (VGPR_Count=64) ->
// spill to scratch -> 202 MB HBM WRITE traffic, 263 us. Now: 32-query tile
// per block, per 64-key round wave w computes S for keys 16w..16w+15 (K via
// 16B quad0 register load), P transposed through double-buffered shared LDS,
// one barrier, then PV channel-split (wave w owns channels 16w..16w+15) with
// V staged in LDS via global_load_lds (16B, XOR-swizzled granules so the
// lane-contiguous DMA write and 2-way-free b128 reads coexist). V fetched
// once per block per round and reused by 32 queries -> L2 traffic halved.
// Persistent VGPRs ~40 -> no spill. Numerics identical to R5 (bound-max
// M = |Q|*max|K'| - 12, f16 P, f16-rounded lsum).

#define N_PIX 9216
#define N_B   2
#define N_C   64

typedef _Float16 half8  __attribute__((ext_vector_type(8)));
typedef _Float16 half4v __attribute__((ext_vector_type(4)));
typedef float    float4v __attribute__((ext_vector_type(4)));

#define LOG2E 1.44269504088896340736f
#define EXP_SHIFT 12.0f

// ---------------------------------------------------------------- k_sigma
__global__ __launch_bounds__(64) void k_sigma(const float* __restrict__ Wq,
                                              const float* __restrict__ Wk,
                                              const float* __restrict__ Wv,
                                              float* __restrict__ sig) {
  __shared__ float G8[8][8];
  __shared__ float Wl[64 * 64];
  __shared__ _Float16 Wh[64 * 80];
  __shared__ _Float16 Gh[64 * 80];
  const int t = threadIdx.x;
  const int mat = blockIdx.x;
  if (mat < 2) {
    const float* W = (mat == 0) ? Wq : Wk;
    const int i = t >> 3, j = t & 7;
    float g = 0.f;
    for (int c = 0; c < 64; ++c) g += W[i * 64 + c] * W[j * 64 + c];
    G8[i][j] = g;
    __syncthreads();
    const int L = t & 7;
    float G0[8], Gr[8];
    for (int k = 0; k < 8; ++k) { G0[k] = G8[L][k]; Gr[k] = G0[k]; }
    for (int it = 0; it < 8; ++it) {
      float g2[8] = {0, 0, 0, 0, 0, 0, 0, 0};
      for (int k = 0; k < 8; ++k) {
        float gik = Gr[k];
        for (int jj = 0; jj < 8; ++jj) g2[jj] += gik * __shfl(Gr[jj], k, 64);
      }
      float mx = 0.f;
      for (int jj = 0; jj < 8; ++jj) mx = fmaxf(mx, fabsf(g2[jj]));
      for (int d = 1; d < 8; d <<= 1) mx = fmaxf(mx, __shfl_xor(mx, d, 64));
      float r = 1.f / mx;
      for (int jj = 0; jj < 8; ++jj) Gr[jj] = g2[jj] * r;
    }
    float u = 0.f;
    for (int jj = 0; jj < 8; ++jj) u += Gr[jj];
    float y = 0.f;
    for (int k = 0; k < 8; ++k) y += G0[k] * __shfl(u, k, 64);
    float nu = u * y, de = u * u;
    for (int d = 1; d < 8; d <<= 1) { nu += __shfl_xor(nu, d, 64); de += __shfl_xor(de, d, 64); }
    if (t == 0) sig[mat] = sqrtf(nu / de);
  } else {
    for (int idx = t; idx < 4096; idx += 64) Wl[idx] = Wv[idx];
    __syncthreads();
    for (int idx = t; idx < 4096; idx += 64) Wh[(idx >> 6) * 80 + (idx & 63)] = (_Float16)Wl[idx];
    __syncthreads();
    const int lane15 = t & 15, quad = t >> 4;
    half8 fr[4][2];
    for (int rb = 0; rb < 4; ++rb)
      for (int kc = 0; kc < 2; ++kc)
        fr[rb][kc] = *(const half8*)&Wh[(lane15 + 16 * rb) * 80 + 32 * kc + 8 * quad];
    float4v D[4][4];
    for (int mb = 0; mb < 4; ++mb) for (int nb = 0; nb < 4; ++nb) D[mb][nb] = (float4v){0.f, 0.f, 0.f, 0.f};
    for (int kc = 0; kc < 2; ++kc)
      for (int mb = 0; mb < 4; ++mb)
        for (int nb = 0; nb < 4; ++nb)
          D[mb][nb] = __builtin_amdgcn_mfma_f32_16x16x32_f16(fr[mb][kc], fr[nb][kc], D[mb][nb], 0, 0, 0);
    for (int it = 0; it < 8; ++it) {
      float mx = 0.f;
      for (int mb = 0; mb < 4; ++mb) for (int nb = 0; nb < 4; ++nb) for (int r = 0; r < 4; ++r)
        mx = fmaxf(mx, fabsf(D[mb][nb][r]));
      for (int d = 1; d < 64; d <<= 1) mx = fmaxf(mx, __shfl_xor(mx, d, 64));
      float rs = 1.f / mx;
      for (int mb = 0; mb < 4; ++mb) for (int nb = 0; nb < 4; ++nb) for (int r = 0; r < 4; ++r)
        Gh[(4 * quad + r + 16 * mb) * 80 + lane15 + 16 * nb] = (_Float16)(D[mb][nb][r] * rs);
      __syncthreads();
      if (it == 7) break;
      for (int rb = 0; rb < 4; ++rb)
        for (int kc = 0; kc < 2; ++kc)
          fr[rb][kc] = *(const half8*)&Gh[(lane15 + 16 * rb) * 80 + 32 * kc + 8 * quad];
      for (int mb = 0; mb < 4; ++mb) for (int nb = 0; nb < 4; ++nb) D[mb][nb] = (float4v){0.f, 0.f, 0.f, 0.f};
      for (int kc = 0; kc < 2; ++kc)
        for (int mb = 0; mb < 4; ++mb)
          for (int nb = 0; nb < 4; ++nb)
            D[mb][nb] = __builtin_amdgcn_mfma_f32_16x16x32_f16(fr[mb][kc], fr[nb][kc], D[mb][nb], 0, 0, 0);
      __syncthreads();
    }
    float u = 0.f;
    for (int c = 0; c < 64; ++c) u += (float)Gh[t * 80 + c];
    float z = 0.f;
    for (int i2 = 0; i2 < 64; ++i2) z += Wl[i2 * 64 + t] * __shfl(u, i2, 64);
    float nu = z * z, de = u * u;
    for (int d = 1; d < 64; d <<= 1) { nu += __shfl_xor(nu, d, 64); de += __shfl_xor(de, d, 64); }
    if (t == 0) sig[2] = sqrtf(nu / de);
  }
}

// ---------------------------------------------------------------- k_wconv
__global__ __launch_bounds__(128) void k_wconv(const float* __restrict__ Wq, const float* __restrict__ bq,
                                               const float* __restrict__ Wk, const float* __restrict__ bk,
                                               const float* __restrict__ Wv, const float* __restrict__ bv,
                                               const float* __restrict__ sig,
                                               _Float16* __restrict__ W16, float* __restrict__ b80,
                                               unsigned* __restrict__ maxKu) {
  const float iq = LOG2E / sig[0], ik = 1.0f / sig[1], iv = 1.0f / sig[2];
  const int t = threadIdx.x;
  for (int idx = t; idx < 80 * 64; idx += 128) {
    const int m = idx >> 6, c = idx & 63;
    float v;
    if (m < 8)       v = Wq[m * 64 + c] * iq;
    else if (m < 16) v = Wk[(m - 8) * 64 + c] * ik;
    else             v = Wv[(m - 16) * 64 + c] * iv;
    W16[idx] = (_Float16)v;
  }
  if (t < 80) {
    float v;
    if (t < 8)       v = bq[t] * LOG2E;
    else if (t < 16) v = bk[t - 8];
    else             v = bv[t - 16];
    b80[t] = v;
  }
  if (t < 2) maxKu[t] = 0u;
}

// ---------------------------------------------------------------- k_fgh
__global__ __launch_bounds__(256) void k_fgh(const float* __restrict__ x,
                                             const _Float16* __restrict__ W16,
                                             const float* __restrict__ b80,
                                             _Float16* __restrict__ K16,
                                             _Float16* __restrict__ Q16,
                                             _Float16* __restrict__ VT16,
                                             unsigned* __restrict__ maxKu) {
  const int wave = threadIdx.x >> 6;
  const int lane = threadIdx.x & 63;
  const int lane15 = lane & 15, quad = lane >> 4;
  const int tile = blockIdx.x * 4 + wave;
  const int b = tile / 576;
  const int n = (tile % 576) * 16 + lane15;
  half8 wf[5][2];
  for (int mb = 0; mb < 5; ++mb)
    for (int kc = 0; kc < 2; ++kc)
      wf[mb][kc] = *(const half8*)&W16[(lane15 + 16 * mb) * 64 + 32 * kc + 8 * quad];
  float4v acc[5];
  for (int mb = 0; mb < 5; ++mb) acc[mb] = *(const float4v*)&b80[16 * mb + 4 * quad];
  const float* xb = x + (size_t)b * N_C * N_PIX;
  for (int kc = 0; kc < 2; ++kc) {
    half8 bf;
    for (int j = 0; j < 8; ++j)
      bf[j] = (_Float16)xb[(size_t)(32 * kc + 8 * quad + j) * N_PIX + n];
    for (int mb = 0; mb < 5; ++mb)
      acc[mb] = __builtin_amdgcn_mfma_f32_16x16x32_f16(wf[mb][kc], bf, acc[mb], 0, 0, 0);
  }
  {
    _Float16* dstK = K16 + ((size_t)b * N_PIX + n) * 8;
    _Float16* dstQ = Q16 + ((size_t)b * N_PIX + n) * 8;
    for (int r = 0; r < 4; ++r) {
      const int m = 4 * quad + r;
      const _Float16 v = (_Float16)acc[0][r];
      if (m < 8) dstK[m] = v; else dstQ[m - 8] = v;
    }
  }
  for (int mb = 1; mb < 5; ++mb)
    for (int r = 0; r < 4; ++r) {
      const int c = 4 * quad + r + 16 * (mb - 1);
      VT16[((size_t)b * N_C + c) * N_PIX + n] = (_Float16)acc[mb][r];
    }
  float sq = 0.f;
  if (quad < 2)
    for (int r = 0; r < 4; ++r) sq += acc[0][r] * acc[0][r];
  sq += __shfl_xor(sq, 16, 64);
  for (int d = 1; d < 64; d <<= 1) sq = fmaxf(sq, __shfl_xor(sq, d, 64));
  if (lane == 0) atomicMax(&maxKu[b], __float_as_uint(sq));
}

// ---------------------------------------------------------------- k_attn
// 576 blocks (32 queries each), 4 waves. Per 64-key round:
//   wave w: S for keys [i0+16w, i0+16w+16) x 32 queries (2 MFMAs)
//           -> exp2 -> P transpose into shared Pld[buf]
//   __syncthreads (drains vmcnt: publishes P AND completes V staging)
//   wave w: PV for channels [16w,16w+16) from Vld[buf] (4 MFMAs)
// V staged by global_load_lds (16B/lane), XOR-swizzled granules:
//   granule (row, c16) stored at row*64 + (c16 ^ (row&7))*8 halves.

__device__ __forceinline__ void gload16(const _Float16* g, _Float16* l) {
  __builtin_amdgcn_global_load_lds(
      (const __attribute__((address_space(1))) void*)g,
      (__attribute__((address_space(3))) void*)l, 16, 0, 0);
}

__global__ __launch_bounds__(256, 2) void k_attn(const _Float16* __restrict__ K16,
                                                 const _Float16* __restrict__ Q16,
                                                 const _Float16* __restrict__ VT16,
                                                 const unsigned* __restrict__ maxKu,
                                                 const float* __restrict__ x,
                                                 const float* __restrict__ gamma,
                                                 float* __restrict__ out) {
  __shared__ __align__(16) _Float16 Vld[2][64 * 64];  // 8 KB per buffer
  __shared__ __align__(16) _Float16 Pld[2][32 * 72];  // P, A-layout, padded rows
  __shared__ float Lsh[4][32];
  const int wave = threadIdx.x >> 6;
  const int lane = threadIdx.x & 63;
  const int lane15 = lane & 15, quad = lane >> 4;
  const int tile = blockIdx.x;            // 0..575
  const int b = tile / 288;
  const int jb = (tile % 288) * 32;
  const float gm = gamma[0];
  const _Float16* Kb = K16 + (size_t)b * N_PIX * 8;
  const _Float16* Vb = VT16 + (size_t)b * N_C * N_PIX;
  // staging lane mapping (constant over rounds)
  const int srow = lane >> 3;                   // 0..7
  const int scol = (lane & 7) ^ srow;           // XOR swizzle
  const _Float16* gV0 = Vb + (size_t)(16 * wave + srow) * N_PIX + scol * 8;
  const _Float16* gV1 = Vb + (size_t)(16 * wave + 8 + srow) * N_PIX + scol * 8;

  // Q frags (B-operand): quad0 holds Q[query][k=0..7]; other quads zero.
  half8 qf0 = {}, qf1 = {};
  if (quad == 0) {
    qf0 = *(const half8*)(Q16 + ((size_t)b * N_PIX + jb + lane15) * 8);
    qf1 = *(const half8*)(Q16 + ((size_t)b * N_PIX + jb + 16 + lane15) * 8);
  }
  // bound-max per query (R5 numerics)
  const float maxK = sqrtf(__uint_as_float(maxKu[b]));
  float nq0 = 0.f, nq1 = 0.f;
  if (quad == 0)
#pragma unroll
    for (int j = 0; j < 8; ++j) {
      nq0 += (float)qf0[j] * (float)qf0[j];
      nq1 += (float)qf1[j] * (float)qf1[j];
    }
  nq0 = __shfl(nq0, lane15, 64);
  nq1 = __shfl(nq1, lane15, 64);
  const float M0 = sqrtf(nq0) * maxK - EXP_SHIFT;
  const float M1 = sqrtf(nq1) * maxK - EXP_SHIFT;

  float4v acc0 = {0.f, 0.f, 0.f, 0.f}, acc1 = {0.f, 0.f, 0.f, 0.f};
  float ls0 = 0.f, ls1 = 0.f;
  half8 kA = {}, kB = {};                  // quads 1-3 stay zero forever

  // preload round 0
  gload16(gV0, &Vld[0][(16 * wave) * 64]);
  gload16(gV1, &Vld[0][(16 * wave + 8) * 64]);
  if (quad == 0) kA = *(const half8*)(Kb + (size_t)(16 * wave + lane15) * 8);

  const float4v f4z = {0.f, 0.f, 0.f, 0.f};
#define ROUND(I0, BUF, KF, KN, PREF)                                                       \
  {                                                                                        \
    const int i1 = (I0) + 64;                                                              \
    if (PREF) {                                                                            \
      gload16(gV0 + i1, &Vld[BUF ^ 1][(16 * wave) * 64]);                                  \
      gload16(gV1 + i1, &Vld[BUF ^ 1][(16 * wave + 8) * 64]);                              \
      if (quad == 0) KN = *(const half8*)(Kb + (size_t)(i1 + 16 * wave + lane15) * 8);     \
    }                                                                                      \
    float4v s0 = __builtin_amdgcn_mfma_f32_16x16x32_f16(KF, qf0, f4z, 0, 0, 0);            \
    float4v s1 = __builtin_amdgcn_mfma_f32_16x16x32_f16(KF, qf1, f4z, 0, 0, 0);            \
    half4v h0, h1;                                                                         \
    _Pragma("unroll") for (int r = 0; r < 4; ++r) {                                        \
      const float p0 = __builtin_amdgcn_exp2f(s0[r] - M0);                                 \
      const float p1 = __builtin_amdgcn_exp2f(s1[r] - M1);                                 \
      h0[r] = (_Float16)p0; ls0 += (float)h0[r];                                           \
      h1[r] = (_Float16)p1; ls1 += (float)h1[r];                                           \
    }                                                                                      \
    *(half4v*)&Pld[BUF][lane15 * 72 + 16 * wave + 4 * quad] = h0;                          \
    *(half4v*)&Pld[BUF][(16 + lane15) * 72 + 16 * wave + 4 * quad] = h1;                   \
    __syncthreads();                                                                       \
    const half8 pf00 = *(const half8*)&Pld[BUF][lane15 * 72 + 8 * quad];                   \
    const half8 pf01 = *(const half8*)&Pld[BUF][lane15 * 72 + 32 + 8 * quad];              \
    const half8 pf10 = *(const half8*)&Pld[BUF][(16 + lane15) * 72 + 8 * quad];            \
    const half8 pf11 = *(const half8*)&Pld[BUF][(16 + lane15) * 72 + 32 + 8 * quad];       \
    const half8 vf0 = *(const half8*)&Vld[BUF][(16 * wave + lane15) * 64 +                 \
                                              ((quad ^ (lane15 & 7)) << 3)];               \
    const half8 vf1 = *(const half8*)&Vld[BUF][(16 * wave + lane15) * 64 +                 \
                                              (((4 + quad) ^ (lane15 & 7)) << 3)];         \
    acc0 = __builtin_amdgcn_mfma_f32_16x16x32_f16(pf00, vf0, acc0, 0, 0, 0);               \
    acc0 = __builtin_amdgcn_mfma_f32_16x16x32_f16(pf01, vf1, acc0, 0, 0, 0);               \
    acc1 = __builtin_amdgcn_mfma_f32_16x16x32_f16(pf10, vf0, acc1, 0, 0, 0);               \
    acc1 = __builtin_amdgcn_mfma_f32_16x16x32_f16(pf11, vf1, acc1, 0, 0, 0);               \
  }

#pragma unroll 1
  for (int r2 = 0; r2 < N_PIX / 128; ++r2) {   // 72 double-rounds
    const int i0 = r2 * 128;
    ROUND(i0, 0, kA, kB, true)
    ROUND(i0 + 64, 1, kB, kA, (i0 + 128) < N_PIX)
  }
#undef ROUND

  // lsum merge (tiny); no O merge needed (channel-split ownership).
  ls0 += __shfl_xor(ls0, 16, 64); ls0 += __shfl_xor(ls0, 32, 64);
  ls1 += __shfl_xor(ls1, 16, 64); ls1 += __shfl_xor(ls1, 32, 64);
  if (quad == 0) { Lsh[wave][lane15] = ls0; Lsh[wave][16 + lane15] = ls1; }
  __syncthreads();
  float4v lt0 = {0.f, 0.f, 0.f, 0.f}, lt1 = {0.f, 0.f, 0.f, 0.f};
#pragma unroll
  for (int w = 0; w < 4; ++w) {
    const float4v a = *(const float4v*)&Lsh[w][4 * quad];
    const float4v c = *(const float4v*)&Lsh[w][16 + 4 * quad];
#pragma unroll
    for (int r = 0; r < 4; ++r) { lt0[r] += a[r]; lt1[r] += c[r]; }
  }
  const int ch = 16 * wave + lane15;
  const float* xb = x + (size_t)b * N_C * N_PIX;
  float* ob = out + (size_t)b * N_C * N_PIX;
  {
    const size_t idx = (size_t)ch * N_PIX + jb + 4 * quad;
    const float4v xr = *(const float4v*)(xb + idx);
    float4v o;
#pragma unroll
    for (int r = 0; r < 4; ++r) o[r] = gm * acc0[r] / lt0[r] + xr[r];
    *(float4v*)(ob + idx) = o;
  }
  {
    const size_t idx = (size_t)ch * N_PIX + jb + 16 + 4 * quad;
    const float4v xr = *(const float4v*)(xb + idx);
    float4v o;
#pragma unroll
    for (int r = 0; r < 4; ++r) o[r] = gm * acc1[r] / lt1[r] + xr[r];
    *(float4v*)(ob + idx) = o;
  }
}

// ---------------------------------------------------------------- launch
extern "C" void kernel_launch(void* const* d_in, const int* in_sizes, int n_in,
                              void* d_out, int out_size, void* d_ws, size_t ws_size,
                              hipStream_t stream) {
  const float* x     = (const float*)d_in[0];
  const float* Wq    = (const float*)d_in[1];
  const float* bq    = (const float*)d_in[2];
  const float* Wk    = (const float*)d_in[3];
  const float* bk    = (const float*)d_in[4];
  const float* Wv    = (const float*)d_in[5];
  const float* bv    = (const float*)d_in[6];
  const float* gamma = (const float*)d_in[7];
  float* out = (float*)d_out;

  char* ws = (char*)d_ws;
  float*    sig   = (float*)ws;                       // 4 floats
  unsigned* maxKu = (unsigned*)(ws + 16);             // 2 uints (float bits, >=0)
  float*    b80   = (float*)(ws + 32);                // 80 floats
  _Float16* W16   = (_Float16*)(ws + 512);            // 80*64 halves
  _Float16* K16   = (_Float16*)(ws + 10752);          // 2*9216*8
  _Float16* Q16   = (_Float16*)(ws + 10752 + 294912); // 2*9216*8
  _Float16* VT16  = (_Float16*)(ws + 10752 + 2 * 294912); // 2*64*9216

  hipLaunchKernelGGL(k_sigma, dim3(3), dim3(64), 0, stream, Wq, Wk, Wv, sig);
  hipLaunchKernelGGL(k_wconv, dim3(1), dim3(128), 0, stream, Wq, bq, Wk, bk, Wv, bv, sig, W16, b80, maxKu);
  hipLaunchKernelGGL(k_fgh, dim3(288), dim3(256), 0, stream, x, W16, b80, K16, Q16, VT16, maxKu);
  hipLaunchKernelGGL(k_attn, dim3(576), dim3(256), 0, stream, K16, Q16, VT16, maxKu, x, gamma, out);
}